// Round 15
// baseline (428.465 us; speedup 1.0000x reference)
//
#include <hip/hip_runtime.h>

typedef unsigned short u16;
typedef unsigned int u32;
typedef short s16x8 __attribute__((ext_vector_type(8)));
typedef float f32x4 __attribute__((ext_vector_type(4)));

#define HWN 4096
#define CC  256
#define C2  128
#define LOG2E 1.4426950408889634f

static __device__ __forceinline__ u16 f2bf(float f) {
    union { float f; u32 u; } c; c.f = f;
    u32 u = c.u;
    u32 r = (u + 0x7fffu + ((u >> 16) & 1u)) >> 16;
    return (u16)r;
}
static __device__ __forceinline__ float bf2f(u16 u) {
    union { u32 u; float f; } c; c.u = ((u32)u) << 16; return c.f;
}
static __device__ __forceinline__ u32 cvtpk(float lo, float hi) {
    u32 d;
    asm("v_cvt_pk_bf16_f32 %0, %1, %2" : "=v"(d) : "v"(lo), "v"(hi));
    return d;
}
// native 2^x (v_exp_f32); plain exp2f lowers to the slow OCML polynomial.
static __device__ __forceinline__ float fexp2(float x) {
    return __builtin_amdgcn_exp2f(x);
}

// ---------------- K0: convert weights to bf16 (theta pre-scaled by log2e) -----
__global__ __launch_bounds__(256) void k_wcvt(
    const float* __restrict__ w_th, const float* __restrict__ w_pi,
    const float* __restrict__ w_g,  const float* __restrict__ w_out,
    u16* __restrict__ wthb, u16* __restrict__ wpib,
    u16* __restrict__ wgb,  u16* __restrict__ woutb)
{
    int i = blockIdx.x * 256 + threadIdx.x;
    wthb[i]  = f2bf(w_th[i] * LOG2E);
    wpib[i]  = f2bf(w_pi[i]);
    wgb[i]   = f2bf(w_g[i]);
    woutb[i] = f2bf(w_out[i]);
}

// ---------------- K1: MFMA projections (unchanged from r12) ----------------
__device__ __forceinline__ void load_afrag(const float* __restrict__ px, int g, s16x8 a[8]) {
    #pragma unroll
    for (int ks = 0; ks < 8; ++ks) {
        union { s16x8 v; u16 u[8]; } c;
        #pragma unroll
        for (int j = 0; j < 8; ++j)
            c.u[j] = f2bf(px[(size_t)(ks*32 + g*8 + j) * HWN]);
        a[ks] = c.v;
    }
}

__device__ __forceinline__ void proj_gemm(const s16x8 a[8], const u16* __restrict__ wb,
                                          const float* __restrict__ bias, float bscale,
                                          int m16, int g, f32x4 acc[8]) {
    #pragma unroll
    for (int nb = 0; nb < 8; ++nb) {
        float bv = bias[nb*16 + m16] * bscale;
        acc[nb] = (f32x4){bv, bv, bv, bv};
    }
    #pragma unroll
    for (int ks = 0; ks < 8; ++ks) {
        #pragma unroll
        for (int nb = 0; nb < 8; ++nb) {
            s16x8 bb = *(const s16x8*)&wb[(size_t)(nb*16 + m16)*CC + ks*32 + g*8];
            acc[nb] = __builtin_amdgcn_mfma_f32_16x16x32_bf16(a[ks], bb, acc[nb], 0, 0, 0);
        }
    }
}

__global__ __launch_bounds__(256) void k_projM(
    const float* __restrict__ x1, const float* __restrict__ x2,
    const u16* __restrict__ wthb, const float* __restrict__ b_th,
    const u16* __restrict__ wpib, const float* __restrict__ b_pi,
    const u16* __restrict__ wgb,  const float* __restrict__ b_g,
    u16* __restrict__ e1t, u16* __restrict__ e2t, u16* __restrict__ g2t)
{
    __shared__ u16 gs[C2][72];
    const int tid  = threadIdx.x;
    const int b    = blockIdx.x >> 6;
    const int q0   = (blockIdx.x & 63) * 64;
    const int wid  = __builtin_amdgcn_readfirstlane(tid >> 6);
    const int lane = tid & 63;
    const int m16  = lane & 15;
    const int g    = lane >> 4;

    s16x8 a[8];
    f32x4 acc[8];

    const float* px1 = x1 + (size_t)b*CC*HWN + q0 + wid*16 + m16;
    load_afrag(px1, g, a);
    proj_gemm(a, wthb, b_th, LOG2E, m16, g, acc);
    #pragma unroll
    for (int nb = 0; nb < 8; ++nb)
        #pragma unroll
        for (int r = 0; r < 4; ++r)
            e1t[((size_t)b*HWN + q0 + wid*16 + g*4 + r)*C2 + nb*16 + m16] = f2bf(acc[nb][r]);

    const float* px2 = x2 + (size_t)b*CC*HWN + q0 + wid*16 + m16;
    load_afrag(px2, g, a);
    proj_gemm(a, wpib, b_pi, 1.f, m16, g, acc);
    #pragma unroll
    for (int nb = 0; nb < 8; ++nb)
        #pragma unroll
        for (int r = 0; r < 4; ++r) {
            int q   = q0 + wid*16 + g*4 + r;
            int gix = (nb*2 + (m16 >> 3)) ^ (q & 7);       // baked granule swizzle
            e2t[((size_t)b*HWN + q)*C2 + gix*8 + (m16 & 7)] = f2bf(acc[nb][r]);
        }

    proj_gemm(a, wgb, b_g, 1.f, m16, g, acc);
    #pragma unroll
    for (int nb = 0; nb < 8; ++nb)
        #pragma unroll
        for (int r = 0; r < 4; ++r)
            gs[nb*16 + m16][wid*16 + g*4 + r] = f2bf(acc[nb][r]);
    __syncthreads();
    // tiled + permuted + swizzled copy-out (this block == tile q0>>6)
    u16* gt = g2t + ((size_t)b*64 + (q0 >> 6))*8192;
    #pragma unroll
    for (int r = 0; r < 4; ++r) {
        int idx = r*256 + tid;            // 0..1023 -> row 0..127, c8 0..7
        int row = idx >> 3, c8 = idx & 7;
        union { u16 u[8]; int4 v; } o;
        #pragma unroll
        for (int e = 0; e < 8; ++e) {
            int c  = c8*8 + e;
            int cs = c ^ ((row & 7) << 3);                 // deswizzle dest col
            int kk = cs >> 5, rem = cs & 31;
            int gg = rem >> 3, jj = rem & 7;
            int ko = kk*32 + ((jj >> 2) << 4) + (gg << 2) + (jj & 3);  // k-perm
            o.u[e] = gs[row][ko];
        }
        *(int4*)&gt[row*64 + c8*8] = o.v;
    }
}

// ---------------- K2: flash core — KVBLK=64, k-split 4 (4 blocks/CU),
//   fixed m=0, swapped QK^T, in-register P, native exp2, r12 staging ----------
__global__ __launch_bounds__(256, 4) void k_flash(
    const u16* __restrict__ e1t, const u16* __restrict__ e2t,
    const u16* __restrict__ g2t,
    u16* __restrict__ o0, u16* __restrict__ o1,
    u16* __restrict__ o2, u16* __restrict__ o3,
    float* __restrict__ ms)
{
    __shared__ u16 e2s[64*128];     // [k][c2] swizzled content, linear-staged (16KB)
    __shared__ u16 g2s[128*64];     // [c2][k'] permuted+swizzled, linear-staged (16KB)

    const int tid  = threadIdx.x;
    const int bid  = ((blockIdx.x & 7) << 7) | (blockIdx.x >> 3);  // XCD-chunked, 1024 blocks
    const int b    = bid >> 7;
    const int qb   = (bid >> 2) & 31;
    const int seg  = bid & 3;
    const int q0   = qb * 128;
    const int wid  = __builtin_amdgcn_readfirstlane(tid >> 6);
    const int lane = tid & 63;
    const int m16  = lane & 15;
    const int g    = lane >> 4;
    const int sw16 = (m16 & 7) << 3;

    // e1 fragments (q side), in regs for whole kernel (log2e pre-scaled)
    s16x8 af[2][4];
    #pragma unroll
    for (int h = 0; h < 2; ++h) {
        const u16* p = e1t + ((size_t)b*HWN + q0 + wid*32 + h*16 + m16)*C2 + g*8;
        #pragma unroll
        for (int kc = 0; kc < 4; ++kc) af[h][kc] = *(const s16x8*)(p + kc*32);
    }

    f32x4 acc[2][8];
    #pragma unroll
    for (int h = 0; h < 2; ++h)
        #pragma unroll
        for (int i = 0; i < 8; ++i) acc[h][i] = (f32x4){0.f,0.f,0.f,0.f};
    float s_w = 0.f;

    const u16* e2base = e2t + (size_t)b*HWN*C2;
    const u16* g2base = g2t + (size_t)b*64*8192;
    const int er = tid >> 4, ec = tid & 15;      // e2 staging: row, col16

    for (int it = 0; it < 16; ++it) {
        const int k0 = seg*1024 + it*64;
        __syncthreads();                    // bar1: prev compute done, overwrite ok
        #pragma unroll
        for (int r = 0; r < 4; ++r) {       // stage e2 tile [64][128] (linear dst)
            int row = r*16 + er;
            int4 v = *(const int4*)(e2base + (size_t)(k0 + row)*C2 + ec*8);
            *(int4*)&e2s[row*128 + ec*8] = v;
        }
        {                                   // stage g2 tile: contiguous 16 KB
            const u16* gt = g2base + (size_t)(k0 >> 6)*8192;
            #pragma unroll
            for (int r = 0; r < 4; ++r) {
                int off = (r*256 + tid)*8;
                int4 v = *(const int4*)(gt + off);
                *(int4*)&g2s[off] = v;
            }
        }
        __syncthreads();                    // bar2: tiles ready

        // ---- QK (swapped): S^T, lane m16 = q, regs cover k = j*16+g*4+r
        f32x4 s[2][4];
        #pragma unroll
        for (int h = 0; h < 2; ++h)
            #pragma unroll
            for (int j = 0; j < 4; ++j) s[h][j] = (f32x4){0.f,0.f,0.f,0.f};
        #pragma unroll
        for (int j = 0; j < 4; ++j) {
            #pragma unroll
            for (int kc = 0; kc < 4; ++kc) {
                s16x8 aa = *(const s16x8*)&e2s[((j*16+m16)*128 + kc*32 + g*8) ^ sw16];
                s[0][j] = __builtin_amdgcn_mfma_f32_16x16x32_bf16(aa, af[0][kc], s[0][j], 0, 0, 0);
                s[1][j] = __builtin_amdgcn_mfma_f32_16x16x32_bf16(aa, af[1][kc], s[1][j], 0, 0, 0);
            }
        }

        // ---- softmax with FIXED reference m=0: P = 2^S directly; s dies here
        float psum = 0.f;
        s16x8 pa[2][2];
        #pragma unroll
        for (int h = 0; h < 2; ++h)
            #pragma unroll
            for (int kk = 0; kk < 2; ++kk) {
                float p0 = fexp2(s[h][2*kk][0]);
                float p1 = fexp2(s[h][2*kk][1]);
                float p2 = fexp2(s[h][2*kk][2]);
                float p3 = fexp2(s[h][2*kk][3]);
                float p4 = fexp2(s[h][2*kk+1][0]);
                float p5 = fexp2(s[h][2*kk+1][1]);
                float p6 = fexp2(s[h][2*kk+1][2]);
                float p7 = fexp2(s[h][2*kk+1][3]);
                psum += ((p0 + p1) + (p2 + p3)) + ((p4 + p5) + (p6 + p7));
                union { u32 d[4]; s16x8 v; } pf;
                pf.d[0] = cvtpk(p0, p1);
                pf.d[1] = cvtpk(p2, p3);
                pf.d[2] = cvtpk(p4, p5);
                pf.d[3] = cvtpk(p6, p7);
                pa[h][kk] = pf.v;
            }
        s_w += psum;

        // ---- PV: acc[32q][128c2] += P[32q][64k'] * g2[64k'][128c2]
        #pragma unroll
        for (int kk = 0; kk < 2; ++kk) {
            #pragma unroll
            for (int fc = 0; fc < 8; ++fc) {
                s16x8 gb = *(const s16x8*)&g2s[((fc*16+m16)*64 + kk*32 + g*8) ^ sw16];
                acc[0][fc] = __builtin_amdgcn_mfma_f32_16x16x32_bf16(pa[0][kk], gb, acc[0][fc], 0, 0, 0);
                acc[1][fc] = __builtin_amdgcn_mfma_f32_16x16x32_bf16(pa[1][kk], gb, acc[1][fc], 0, 0, 0);
            }
        }
    }

    // ---- epilogue
    #pragma unroll
    for (int off = 32; off >= 1; off >>= 1) s_w += __shfl_xor(s_w, off);
    if (lane == 0) {
        int idx = b*512 + seg*128 + qb*4 + wid;
        ms[idx*2 + 0] = 0.f;                 // fixed log2-reference
        ms[idx*2 + 1] = s_w;
    }
    const float inv_s = 1.f / s_w;
    u16* op = (seg & 2) ? ((seg & 1) ? o3 : o2) : ((seg & 1) ? o1 : o0);
    #pragma unroll
    for (int h = 0; h < 2; ++h)
        #pragma unroll
        for (int fc = 0; fc < 8; ++fc)
            #pragma unroll
            for (int r = 0; r < 4; ++r)
                op[((size_t)b*HWN + q0 + wid*32 + h*16 + g*4 + r)*C2 + fc*16 + m16] =
                    f2bf(acc[h][fc][r] * inv_s);
}

// ---------------- K3: per-batch (M, Z) from 512 (m,s) pairs (log2 units) ------
__global__ void k_mz(const float* __restrict__ ms, float* __restrict__ mz)
{
    __shared__ float rmax[8], rsum[8];
    const int b = blockIdx.x, tid = threadIdx.x;
    const int lane = tid & 63, wid = tid >> 6;
    float m = ms[((size_t)b*512 + tid)*2 + 0];
    float s = ms[((size_t)b*512 + tid)*2 + 1];
    float mm = m;
    #pragma unroll
    for (int off = 32; off >= 1; off >>= 1) mm = fmaxf(mm, __shfl_xor(mm, off));
    if (lane == 0) rmax[wid] = mm;
    __syncthreads();
    float M = rmax[0];
    #pragma unroll
    for (int i = 1; i < 8; ++i) M = fmaxf(M, rmax[i]);
    float z = s * fexp2(m - M);
    #pragma unroll
    for (int off = 32; off >= 1; off >>= 1) z += __shfl_xor(z, off);
    if (lane == 0) rsum[wid] = z;
    __syncthreads();
    if (tid == 0) {
        float Z = 0.f;
        #pragma unroll
        for (int i = 0; i < 8; ++i) Z += rsum[i];
        mz[b*2] = M; mz[b*2+1] = Z;
    }
}

// ---------------- K4: combine 4 k-split partials + final conv + residual ------
__global__ __launch_bounds__(256) void k_outM(
    const u16* __restrict__ o0, const u16* __restrict__ o1,
    const u16* __restrict__ o2, const u16* __restrict__ o3,
    const float* __restrict__ ms, const float* __restrict__ mz,
    const u16* __restrict__ woutb, const float* __restrict__ b_out,
    const float* __restrict__ x1, float* __restrict__ out)
{
    const int tid  = threadIdx.x;
    const int b    = blockIdx.x >> 6;
    const int q0   = (blockIdx.x & 63) * 64;
    const int wv   = tid >> 6;
    const int lane = tid & 63;
    const int m16  = lane & 15;
    const int g    = lane >> 4;
    const int q    = q0 + wv*16 + m16;

    const float M    = mz[b*2];
    const float invZ = 1.f / mz[b*2+1];
    const int idx5   = (q0 >> 5) + (wv >> 1);   // 32q-group index within batch
    float al[4];
    #pragma unroll
    for (int i = 0; i < 4; ++i) {
        const float* msp = ms + ((size_t)b*512 + i*128 + idx5)*2;
        al[i] = msp[1] * fexp2(msp[0] - M) * invZ;
    }

    s16x8 bfr[4];
    #pragma unroll
    for (int ks = 0; ks < 4; ++ks) {
        union { s16x8 v; u16 u[8]; } v0, v1, v2, v3, oc;
        size_t base = ((size_t)b*HWN + q)*C2 + ks*32 + g*8;
        v0.v = *(const s16x8*)&o0[base];
        v1.v = *(const s16x8*)&o1[base];
        v2.v = *(const s16x8*)&o2[base];
        v3.v = *(const s16x8*)&o3[base];
        #pragma unroll
        for (int j = 0; j < 8; ++j)
            oc.u[j] = f2bf((al[0]*bf2f(v0.u[j]) + al[1]*bf2f(v1.u[j]))
                         + (al[2]*bf2f(v2.u[j]) + al[3]*bf2f(v3.u[j])));
        bfr[ks] = oc.v;
    }

    f32x4 acc[16];
    #pragma unroll
    for (int cb = 0; cb < 16; ++cb) acc[cb] = (f32x4){0.f,0.f,0.f,0.f};
    #pragma unroll
    for (int ks = 0; ks < 4; ++ks) {
        #pragma unroll
        for (int cb = 0; cb < 16; ++cb) {
            s16x8 afr = *(const s16x8*)&woutb[(size_t)(cb*16 + m16)*C2 + ks*32 + g*8];
            acc[cb] = __builtin_amdgcn_mfma_f32_16x16x32_bf16(afr, bfr[ks], acc[cb], 0, 0, 0);
        }
    }

    #pragma unroll
    for (int cb = 0; cb < 16; ++cb) {
        f32x4 bb = *(const f32x4*)&b_out[cb*16 + g*4];
        #pragma unroll
        for (int r = 0; r < 4; ++r) {
            int co = cb*16 + g*4 + r;
            size_t o = ((size_t)b*CC + co)*HWN + q;
            out[o] = acc[cb][r] + bb[r] + x1[o];
        }
    }
}

extern "C" void kernel_launch(void* const* d_in, const int* in_sizes, int n_in,
                              void* d_out, int out_size, void* d_ws, size_t ws_size,
                              hipStream_t stream)
{
    const float* x1   = (const float*)d_in[0];
    const float* x2   = (const float*)d_in[1];
    const float* w_th = (const float*)d_in[2];
    const float* b_th = (const float*)d_in[3];
    const float* w_pi = (const float*)d_in[4];
    const float* b_pi = (const float*)d_in[5];
    const float* w_g  = (const float*)d_in[6];
    const float* b_g  = (const float*)d_in[7];
    const float* w_out= (const float*)d_in[8];
    const float* b_out= (const float*)d_in[9];
    float* out = (float*)d_out;

    char* ws = (char*)d_ws;
    u16*   e1t  = (u16*)(ws);                    // 8 MiB  bf16 [B][HW][C2]
    u16*   e2t  = (u16*)(ws + 8388608);          // 8 MiB  bf16 [B][HW][C2] (swizzled)
    u16*   g2t  = (u16*)(ws + 16777216);         // 8 MiB  bf16 [B][64][128][64] tiled
    u16*   op0  = (u16*)(ws + 25165824);         // 8 MiB  bf16 seg0 partial
    u16*   op1  = (u16*)(ws + 33554432);         // 8 MiB  bf16 seg1 partial
    u16*   op2  = (u16*)(ws + 41943040);         // 8 MiB  bf16 seg2 partial
    u16*   op3  = (u16*)(ws + 50331648);         // 8 MiB  bf16 seg3 partial
    float* ms   = (float*)(ws + 58720256);       // 32 KiB f32  [B][512][2]
    float* mz   = (float*)(ws + 58753024);       // 64 B   f32  [B][2]
    u16*   wthb = (u16*)(ws + 58753152);         // 64 KiB bf16 [C2][CC] (log2e-scaled)
    u16*   wpib = (u16*)(ws + 58818688);         // 64 KiB
    u16*   wgb  = (u16*)(ws + 58884224);         // 64 KiB
    u16*   woutb= (u16*)(ws + 58949760);         // 64 KiB bf16 [CC][C2]

    k_wcvt <<<dim3(128),  dim3(256), 0, stream>>>(w_th, w_pi, w_g, w_out, wthb, wpib, wgb, woutb);
    k_projM<<<dim3(512),  dim3(256), 0, stream>>>(x1, x2, wthb, b_th, wpib, b_pi, wgb, b_g,
                                                  e1t, e2t, g2t);
    k_flash<<<dim3(1024), dim3(256), 0, stream>>>(e1t, e2t, g2t, op0, op1, op2, op3, ms);
    k_mz   <<<dim3(8),    dim3(512), 0, stream>>>(ms, mz);
    k_outM <<<dim3(512),  dim3(256), 0, stream>>>(op0, op1, op2, op3, ms, mz, woutb, b_out, x1, out);
}

// Round 16
// 188.301 us; speedup vs baseline: 2.2754x; 2.2754x over previous
//
#include <hip/hip_runtime.h>

typedef unsigned short u16;
typedef unsigned int u32;
typedef short s16x8 __attribute__((ext_vector_type(8)));
typedef float f32x4 __attribute__((ext_vector_type(4)));

#define HWN 4096
#define CC  256
#define C2  128
#define LOG2E 1.4426950408889634f

static __device__ __forceinline__ u16 f2bf(float f) {
    union { float f; u32 u; } c; c.f = f;
    u32 u = c.u;
    u32 r = (u + 0x7fffu + ((u >> 16) & 1u)) >> 16;
    return (u16)r;
}
static __device__ __forceinline__ float bf2f(u16 u) {
    union { u32 u; float f; } c; c.u = ((u32)u) << 16; return c.f;
}
static __device__ __forceinline__ u32 cvtpk(float lo, float hi) {
    u32 d;
    asm("v_cvt_pk_bf16_f32 %0, %1, %2" : "=v"(d) : "v"(lo), "v"(hi));
    return d;
}
// native 2^x (v_exp_f32); plain exp2f lowers to the slow OCML polynomial.
static __device__ __forceinline__ float fexp2(float x) {
    return __builtin_amdgcn_exp2f(x);
}

// ---------------- K0: convert weights to bf16 (theta pre-scaled by log2e) -----
__global__ __launch_bounds__(256) void k_wcvt(
    const float* __restrict__ w_th, const float* __restrict__ w_pi,
    const float* __restrict__ w_g,  const float* __restrict__ w_out,
    u16* __restrict__ wthb, u16* __restrict__ wpib,
    u16* __restrict__ wgb,  u16* __restrict__ woutb)
{
    int i = blockIdx.x * 256 + threadIdx.x;
    wthb[i]  = f2bf(w_th[i] * LOG2E);
    wpib[i]  = f2bf(w_pi[i]);
    wgb[i]   = f2bf(w_g[i]);
    woutb[i] = f2bf(w_out[i]);
}

// ---------------- K1: MFMA projections (unchanged from r12) ----------------
__device__ __forceinline__ void load_afrag(const float* __restrict__ px, int g, s16x8 a[8]) {
    #pragma unroll
    for (int ks = 0; ks < 8; ++ks) {
        union { s16x8 v; u16 u[8]; } c;
        #pragma unroll
        for (int j = 0; j < 8; ++j)
            c.u[j] = f2bf(px[(size_t)(ks*32 + g*8 + j) * HWN]);
        a[ks] = c.v;
    }
}

__device__ __forceinline__ void proj_gemm(const s16x8 a[8], const u16* __restrict__ wb,
                                          const float* __restrict__ bias, float bscale,
                                          int m16, int g, f32x4 acc[8]) {
    #pragma unroll
    for (int nb = 0; nb < 8; ++nb) {
        float bv = bias[nb*16 + m16] * bscale;
        acc[nb] = (f32x4){bv, bv, bv, bv};
    }
    #pragma unroll
    for (int ks = 0; ks < 8; ++ks) {
        #pragma unroll
        for (int nb = 0; nb < 8; ++nb) {
            s16x8 bb = *(const s16x8*)&wb[(size_t)(nb*16 + m16)*CC + ks*32 + g*8];
            acc[nb] = __builtin_amdgcn_mfma_f32_16x16x32_bf16(a[ks], bb, acc[nb], 0, 0, 0);
        }
    }
}

__global__ __launch_bounds__(256) void k_projM(
    const float* __restrict__ x1, const float* __restrict__ x2,
    const u16* __restrict__ wthb, const float* __restrict__ b_th,
    const u16* __restrict__ wpib, const float* __restrict__ b_pi,
    const u16* __restrict__ wgb,  const float* __restrict__ b_g,
    u16* __restrict__ e1t, u16* __restrict__ e2t, u16* __restrict__ g2t)
{
    __shared__ u16 gs[C2][72];
    const int tid  = threadIdx.x;
    const int b    = blockIdx.x >> 6;
    const int q0   = (blockIdx.x & 63) * 64;
    const int wid  = __builtin_amdgcn_readfirstlane(tid >> 6);
    const int lane = tid & 63;
    const int m16  = lane & 15;
    const int g    = lane >> 4;

    s16x8 a[8];
    f32x4 acc[8];

    const float* px1 = x1 + (size_t)b*CC*HWN + q0 + wid*16 + m16;
    load_afrag(px1, g, a);
    proj_gemm(a, wthb, b_th, LOG2E, m16, g, acc);
    #pragma unroll
    for (int nb = 0; nb < 8; ++nb)
        #pragma unroll
        for (int r = 0; r < 4; ++r)
            e1t[((size_t)b*HWN + q0 + wid*16 + g*4 + r)*C2 + nb*16 + m16] = f2bf(acc[nb][r]);

    const float* px2 = x2 + (size_t)b*CC*HWN + q0 + wid*16 + m16;
    load_afrag(px2, g, a);
    proj_gemm(a, wpib, b_pi, 1.f, m16, g, acc);
    #pragma unroll
    for (int nb = 0; nb < 8; ++nb)
        #pragma unroll
        for (int r = 0; r < 4; ++r) {
            int q   = q0 + wid*16 + g*4 + r;
            int gix = (nb*2 + (m16 >> 3)) ^ (q & 7);       // baked granule swizzle
            e2t[((size_t)b*HWN + q)*C2 + gix*8 + (m16 & 7)] = f2bf(acc[nb][r]);
        }

    proj_gemm(a, wgb, b_g, 1.f, m16, g, acc);
    #pragma unroll
    for (int nb = 0; nb < 8; ++nb)
        #pragma unroll
        for (int r = 0; r < 4; ++r)
            gs[nb*16 + m16][wid*16 + g*4 + r] = f2bf(acc[nb][r]);
    __syncthreads();
    // tiled + permuted + swizzled copy-out (this block == tile q0>>6)
    u16* gt = g2t + ((size_t)b*64 + (q0 >> 6))*8192;
    #pragma unroll
    for (int r = 0; r < 4; ++r) {
        int idx = r*256 + tid;            // 0..1023 -> row 0..127, c8 0..7
        int row = idx >> 3, c8 = idx & 7;
        union { u16 u[8]; int4 v; } o;
        #pragma unroll
        for (int e = 0; e < 8; ++e) {
            int c  = c8*8 + e;
            int cs = c ^ ((row & 7) << 3);                 // deswizzle dest col
            int kk = cs >> 5, rem = cs & 31;
            int gg = rem >> 3, jj = rem & 7;
            int ko = kk*32 + ((jj >> 2) << 4) + (gg << 2) + (jj & 3);  // k-perm
            o.u[e] = gs[row][ko];
        }
        *(int4*)&gt[row*64 + c8*8] = o.v;
    }
}

// ---------------- K2: flash core — KVBLK=64, k-split 4, natural VGPR alloc
//   (~108 regs -> 4 waves/SIMD -> 4 blocks/CU), fixed m=0, swapped QK^T,
//   in-register P, native exp2, r12 staging ----------------------------------
__global__ __launch_bounds__(256) void k_flash(
    const u16* __restrict__ e1t, const u16* __restrict__ e2t,
    const u16* __restrict__ g2t,
    u16* __restrict__ o0, u16* __restrict__ o1,
    u16* __restrict__ o2, u16* __restrict__ o3,
    float* __restrict__ ms)
{
    __shared__ u16 e2s[64*128];     // [k][c2] swizzled content, linear-staged (16KB)
    __shared__ u16 g2s[128*64];     // [c2][k'] permuted+swizzled, linear-staged (16KB)

    const int tid  = threadIdx.x;
    const int bid  = ((blockIdx.x & 7) << 7) | (blockIdx.x >> 3);  // XCD-chunked, 1024 blocks
    const int b    = bid >> 7;
    const int qb   = (bid >> 2) & 31;
    const int seg  = bid & 3;
    const int q0   = qb * 128;
    const int wid  = __builtin_amdgcn_readfirstlane(tid >> 6);
    const int lane = tid & 63;
    const int m16  = lane & 15;
    const int g    = lane >> 4;
    const int sw16 = (m16 & 7) << 3;

    // e1 fragments (q side), in regs for whole kernel (log2e pre-scaled)
    s16x8 af[2][4];
    #pragma unroll
    for (int h = 0; h < 2; ++h) {
        const u16* p = e1t + ((size_t)b*HWN + q0 + wid*32 + h*16 + m16)*C2 + g*8;
        #pragma unroll
        for (int kc = 0; kc < 4; ++kc) af[h][kc] = *(const s16x8*)(p + kc*32);
    }

    f32x4 acc[2][8];
    #pragma unroll
    for (int h = 0; h < 2; ++h)
        #pragma unroll
        for (int i = 0; i < 8; ++i) acc[h][i] = (f32x4){0.f,0.f,0.f,0.f};
    float s_w = 0.f;

    const u16* e2base = e2t + (size_t)b*HWN*C2;
    const u16* g2base = g2t + (size_t)b*64*8192;
    const int er = tid >> 4, ec = tid & 15;      // e2 staging: row, col16

    for (int it = 0; it < 16; ++it) {
        const int k0 = seg*1024 + it*64;
        __syncthreads();                    // bar1: prev compute done, overwrite ok
        #pragma unroll
        for (int r = 0; r < 4; ++r) {       // stage e2 tile [64][128] (linear dst)
            int row = r*16 + er;
            int4 v = *(const int4*)(e2base + (size_t)(k0 + row)*C2 + ec*8);
            *(int4*)&e2s[row*128 + ec*8] = v;
        }
        {                                   // stage g2 tile: contiguous 16 KB
            const u16* gt = g2base + (size_t)(k0 >> 6)*8192;
            #pragma unroll
            for (int r = 0; r < 4; ++r) {
                int off = (r*256 + tid)*8;
                int4 v = *(const int4*)(gt + off);
                *(int4*)&g2s[off] = v;
            }
        }
        __syncthreads();                    // bar2: tiles ready

        // ---- QK (swapped): S^T, lane m16 = q, regs cover k = j*16+g*4+r
        f32x4 s[2][4];
        #pragma unroll
        for (int h = 0; h < 2; ++h)
            #pragma unroll
            for (int j = 0; j < 4; ++j) s[h][j] = (f32x4){0.f,0.f,0.f,0.f};
        #pragma unroll
        for (int j = 0; j < 4; ++j) {
            #pragma unroll
            for (int kc = 0; kc < 4; ++kc) {
                s16x8 aa = *(const s16x8*)&e2s[((j*16+m16)*128 + kc*32 + g*8) ^ sw16];
                s[0][j] = __builtin_amdgcn_mfma_f32_16x16x32_bf16(aa, af[0][kc], s[0][j], 0, 0, 0);
                s[1][j] = __builtin_amdgcn_mfma_f32_16x16x32_bf16(aa, af[1][kc], s[1][j], 0, 0, 0);
            }
        }

        // ---- softmax with FIXED reference m=0: P = 2^S directly; s dies here
        float psum = 0.f;
        s16x8 pa[2][2];
        #pragma unroll
        for (int h = 0; h < 2; ++h)
            #pragma unroll
            for (int kk = 0; kk < 2; ++kk) {
                float p0 = fexp2(s[h][2*kk][0]);
                float p1 = fexp2(s[h][2*kk][1]);
                float p2 = fexp2(s[h][2*kk][2]);
                float p3 = fexp2(s[h][2*kk][3]);
                float p4 = fexp2(s[h][2*kk+1][0]);
                float p5 = fexp2(s[h][2*kk+1][1]);
                float p6 = fexp2(s[h][2*kk+1][2]);
                float p7 = fexp2(s[h][2*kk+1][3]);
                psum += ((p0 + p1) + (p2 + p3)) + ((p4 + p5) + (p6 + p7));
                union { u32 d[4]; s16x8 v; } pf;
                pf.d[0] = cvtpk(p0, p1);
                pf.d[1] = cvtpk(p2, p3);
                pf.d[2] = cvtpk(p4, p5);
                pf.d[3] = cvtpk(p6, p7);
                pa[h][kk] = pf.v;
            }
        s_w += psum;

        // ---- PV: acc[32q][128c2] += P[32q][64k'] * g2[64k'][128c2]
        #pragma unroll
        for (int kk = 0; kk < 2; ++kk) {
            #pragma unroll
            for (int fc = 0; fc < 8; ++fc) {
                s16x8 gb = *(const s16x8*)&g2s[((fc*16+m16)*64 + kk*32 + g*8) ^ sw16];
                acc[0][fc] = __builtin_amdgcn_mfma_f32_16x16x32_bf16(pa[0][kk], gb, acc[0][fc], 0, 0, 0);
                acc[1][fc] = __builtin_amdgcn_mfma_f32_16x16x32_bf16(pa[1][kk], gb, acc[1][fc], 0, 0, 0);
            }
        }
    }

    // ---- epilogue
    #pragma unroll
    for (int off = 32; off >= 1; off >>= 1) s_w += __shfl_xor(s_w, off);
    if (lane == 0) {
        int idx = b*512 + seg*128 + qb*4 + wid;
        ms[idx*2 + 0] = 0.f;                 // fixed log2-reference
        ms[idx*2 + 1] = s_w;
    }
    const float inv_s = 1.f / s_w;
    u16* op = (seg & 2) ? ((seg & 1) ? o3 : o2) : ((seg & 1) ? o1 : o0);
    #pragma unroll
    for (int h = 0; h < 2; ++h)
        #pragma unroll
        for (int fc = 0; fc < 8; ++fc)
            #pragma unroll
            for (int r = 0; r < 4; ++r)
                op[((size_t)b*HWN + q0 + wid*32 + h*16 + g*4 + r)*C2 + fc*16 + m16] =
                    f2bf(acc[h][fc][r] * inv_s);
}

// ---------------- K3: per-batch (M, Z) from 512 (m,s) pairs (log2 units) ------
__global__ void k_mz(const float* __restrict__ ms, float* __restrict__ mz)
{
    __shared__ float rmax[8], rsum[8];
    const int b = blockIdx.x, tid = threadIdx.x;
    const int lane = tid & 63, wid = tid >> 6;
    float m = ms[((size_t)b*512 + tid)*2 + 0];
    float s = ms[((size_t)b*512 + tid)*2 + 1];
    float mm = m;
    #pragma unroll
    for (int off = 32; off >= 1; off >>= 1) mm = fmaxf(mm, __shfl_xor(mm, off));
    if (lane == 0) rmax[wid] = mm;
    __syncthreads();
    float M = rmax[0];
    #pragma unroll
    for (int i = 1; i < 8; ++i) M = fmaxf(M, rmax[i]);
    float z = s * fexp2(m - M);
    #pragma unroll
    for (int off = 32; off >= 1; off >>= 1) z += __shfl_xor(z, off);
    if (lane == 0) rsum[wid] = z;
    __syncthreads();
    if (tid == 0) {
        float Z = 0.f;
        #pragma unroll
        for (int i = 0; i < 8; ++i) Z += rsum[i];
        mz[b*2] = M; mz[b*2+1] = Z;
    }
}

// ---------------- K4: combine 4 k-split partials + final conv + residual ------
__global__ __launch_bounds__(256) void k_outM(
    const u16* __restrict__ o0, const u16* __restrict__ o1,
    const u16* __restrict__ o2, const u16* __restrict__ o3,
    const float* __restrict__ ms, const float* __restrict__ mz,
    const u16* __restrict__ woutb, const float* __restrict__ b_out,
    const float* __restrict__ x1, float* __restrict__ out)
{
    const int tid  = threadIdx.x;
    const int b    = blockIdx.x >> 6;
    const int q0   = (blockIdx.x & 63) * 64;
    const int wv   = tid >> 6;
    const int lane = tid & 63;
    const int m16  = lane & 15;
    const int g    = lane >> 4;
    const int q    = q0 + wv*16 + m16;

    const float M    = mz[b*2];
    const float invZ = 1.f / mz[b*2+1];
    const int idx5   = (q0 >> 5) + (wv >> 1);   // 32q-group index within batch
    float al[4];
    #pragma unroll
    for (int i = 0; i < 4; ++i) {
        const float* msp = ms + ((size_t)b*512 + i*128 + idx5)*2;
        al[i] = msp[1] * fexp2(msp[0] - M) * invZ;
    }

    s16x8 bfr[4];
    #pragma unroll
    for (int ks = 0; ks < 4; ++ks) {
        union { s16x8 v; u16 u[8]; } v0, v1, v2, v3, oc;
        size_t base = ((size_t)b*HWN + q)*C2 + ks*32 + g*8;
        v0.v = *(const s16x8*)&o0[base];
        v1.v = *(const s16x8*)&o1[base];
        v2.v = *(const s16x8*)&o2[base];
        v3.v = *(const s16x8*)&o3[base];
        #pragma unroll
        for (int j = 0; j < 8; ++j)
            oc.u[j] = f2bf((al[0]*bf2f(v0.u[j]) + al[1]*bf2f(v1.u[j]))
                         + (al[2]*bf2f(v2.u[j]) + al[3]*bf2f(v3.u[j])));
        bfr[ks] = oc.v;
    }

    f32x4 acc[16];
    #pragma unroll
    for (int cb = 0; cb < 16; ++cb) acc[cb] = (f32x4){0.f,0.f,0.f,0.f};
    #pragma unroll
    for (int ks = 0; ks < 4; ++ks) {
        #pragma unroll
        for (int cb = 0; cb < 16; ++cb) {
            s16x8 afr = *(const s16x8*)&woutb[(size_t)(cb*16 + m16)*C2 + ks*32 + g*8];
            acc[cb] = __builtin_amdgcn_mfma_f32_16x16x32_bf16(afr, bfr[ks], acc[cb], 0, 0, 0);
        }
    }

    #pragma unroll
    for (int cb = 0; cb < 16; ++cb) {
        f32x4 bb = *(const f32x4*)&b_out[cb*16 + g*4];
        #pragma unroll
        for (int r = 0; r < 4; ++r) {
            int co = cb*16 + g*4 + r;
            size_t o = ((size_t)b*CC + co)*HWN + q;
            out[o] = acc[cb][r] + bb[r] + x1[o];
        }
    }
}

extern "C" void kernel_launch(void* const* d_in, const int* in_sizes, int n_in,
                              void* d_out, int out_size, void* d_ws, size_t ws_size,
                              hipStream_t stream)
{
    const float* x1   = (const float*)d_in[0];
    const float* x2   = (const float*)d_in[1];
    const float* w_th = (const float*)d_in[2];
    const float* b_th = (const float*)d_in[3];
    const float* w_pi = (const float*)d_in[4];
    const float* b_pi = (const float*)d_in[5];
    const float* w_g  = (const float*)d_in[6];
    const float* b_g  = (const float*)d_in[7];
    const float* w_out= (const float*)d_in[8];
    const float* b_out= (const float*)d_in[9];
    float* out = (float*)d_out;

    char* ws = (char*)d_ws;
    u16*   e1t  = (u16*)(ws);                    // 8 MiB  bf16 [B][HW][C2]
    u16*   e2t  = (u16*)(ws + 8388608);          // 8 MiB  bf16 [B][HW][C2] (swizzled)
    u16*   g2t  = (u16*)(ws + 16777216);         // 8 MiB  bf16 [B][64][128][64] tiled
    u16*   op0  = (u16*)(ws + 25165824);         // 8 MiB  bf16 seg0 partial
    u16*   op1  = (u16*)(ws + 33554432);         // 8 MiB  bf16 seg1 partial
    u16*   op2  = (u16*)(ws + 41943040);         // 8 MiB  bf16 seg2 partial
    u16*   op3  = (u16*)(ws + 50331648);         // 8 MiB  bf16 seg3 partial
    float* ms   = (float*)(ws + 58720256);       // 32 KiB f32  [B][512][2]
    float* mz   = (float*)(ws + 58753024);       // 64 B   f32  [B][2]
    u16*   wthb = (u16*)(ws + 58753152);         // 64 KiB bf16 [C2][CC] (log2e-scaled)
    u16*   wpib = (u16*)(ws + 58818688);         // 64 KiB
    u16*   wgb  = (u16*)(ws + 58884224);         // 64 KiB
    u16*   woutb= (u16*)(ws + 58949760);         // 64 KiB bf16 [CC][C2]

    k_wcvt <<<dim3(128),  dim3(256), 0, stream>>>(w_th, w_pi, w_g, w_out, wthb, wpib, wgb, woutb);
    k_projM<<<dim3(512),  dim3(256), 0, stream>>>(x1, x2, wthb, b_th, wpib, b_pi, wgb, b_g,
                                                  e1t, e2t, g2t);
    k_flash<<<dim3(1024), dim3(256), 0, stream>>>(e1t, e2t, g2t, op0, op1, op2, op3, ms);
    k_mz   <<<dim3(8),    dim3(512), 0, stream>>>(ms, mz);
    k_outM <<<dim3(512),  dim3(256), 0, stream>>>(op0, op1, op2, op3, ms, mz, woutb, b_out, x1, out);
}

// Round 17
// 176.963 us; speedup vs baseline: 2.4212x; 1.0641x over previous
//
#include <hip/hip_runtime.h>

typedef unsigned short u16;
typedef unsigned int u32;
typedef short s16x8 __attribute__((ext_vector_type(8)));
typedef float f32x4 __attribute__((ext_vector_type(4)));

#define HWN 4096
#define CC  256
#define C2  128
#define LOG2E 1.4426950408889634f

static __device__ __forceinline__ u16 f2bf(float f) {
    union { float f; u32 u; } c; c.f = f;
    u32 u = c.u;
    u32 r = (u + 0x7fffu + ((u >> 16) & 1u)) >> 16;
    return (u16)r;
}
static __device__ __forceinline__ float bf2f(u16 u) {
    union { u32 u; float f; } c; c.u = ((u32)u) << 16; return c.f;
}
static __device__ __forceinline__ u32 cvtpk(float lo, float hi) {
    u32 d;
    asm("v_cvt_pk_bf16_f32 %0, %1, %2" : "=v"(d) : "v"(lo), "v"(hi));
    return d;
}
// native 2^x (v_exp_f32); plain exp2f lowers to the slow OCML polynomial.
static __device__ __forceinline__ float fexp2(float x) {
    return __builtin_amdgcn_exp2f(x);
}

// ---------------- K0: convert weights to bf16 (theta pre-scaled by log2e) -----
__global__ __launch_bounds__(256) void k_wcvt(
    const float* __restrict__ w_th, const float* __restrict__ w_pi,
    const float* __restrict__ w_g,  const float* __restrict__ w_out,
    u16* __restrict__ wthb, u16* __restrict__ wpib,
    u16* __restrict__ wgb,  u16* __restrict__ woutb)
{
    int i = blockIdx.x * 256 + threadIdx.x;
    wthb[i]  = f2bf(w_th[i] * LOG2E);
    wpib[i]  = f2bf(w_pi[i]);
    wgb[i]   = f2bf(w_g[i]);
    woutb[i] = f2bf(w_out[i]);
}

// ---------------- K1: MFMA projections (r12, unchanged) ----------------
__device__ __forceinline__ void load_afrag(const float* __restrict__ px, int g, s16x8 a[8]) {
    #pragma unroll
    for (int ks = 0; ks < 8; ++ks) {
        union { s16x8 v; u16 u[8]; } c;
        #pragma unroll
        for (int j = 0; j < 8; ++j)
            c.u[j] = f2bf(px[(size_t)(ks*32 + g*8 + j) * HWN]);
        a[ks] = c.v;
    }
}

__device__ __forceinline__ void proj_gemm(const s16x8 a[8], const u16* __restrict__ wb,
                                          const float* __restrict__ bias, float bscale,
                                          int m16, int g, f32x4 acc[8]) {
    #pragma unroll
    for (int nb = 0; nb < 8; ++nb) {
        float bv = bias[nb*16 + m16] * bscale;
        acc[nb] = (f32x4){bv, bv, bv, bv};
    }
    #pragma unroll
    for (int ks = 0; ks < 8; ++ks) {
        #pragma unroll
        for (int nb = 0; nb < 8; ++nb) {
            s16x8 bb = *(const s16x8*)&wb[(size_t)(nb*16 + m16)*CC + ks*32 + g*8];
            acc[nb] = __builtin_amdgcn_mfma_f32_16x16x32_bf16(a[ks], bb, acc[nb], 0, 0, 0);
        }
    }
}

__global__ __launch_bounds__(256) void k_projM(
    const float* __restrict__ x1, const float* __restrict__ x2,
    const u16* __restrict__ wthb, const float* __restrict__ b_th,
    const u16* __restrict__ wpib, const float* __restrict__ b_pi,
    const u16* __restrict__ wgb,  const float* __restrict__ b_g,
    u16* __restrict__ e1t, u16* __restrict__ e2t, u16* __restrict__ g2t)
{
    __shared__ u16 gs[C2][72];
    const int tid  = threadIdx.x;
    const int b    = blockIdx.x >> 6;
    const int q0   = (blockIdx.x & 63) * 64;
    const int wid  = __builtin_amdgcn_readfirstlane(tid >> 6);
    const int lane = tid & 63;
    const int m16  = lane & 15;
    const int g    = lane >> 4;

    s16x8 a[8];
    f32x4 acc[8];

    const float* px1 = x1 + (size_t)b*CC*HWN + q0 + wid*16 + m16;
    load_afrag(px1, g, a);
    proj_gemm(a, wthb, b_th, LOG2E, m16, g, acc);
    #pragma unroll
    for (int nb = 0; nb < 8; ++nb)
        #pragma unroll
        for (int r = 0; r < 4; ++r)
            e1t[((size_t)b*HWN + q0 + wid*16 + g*4 + r)*C2 + nb*16 + m16] = f2bf(acc[nb][r]);

    const float* px2 = x2 + (size_t)b*CC*HWN + q0 + wid*16 + m16;
    load_afrag(px2, g, a);
    proj_gemm(a, wpib, b_pi, 1.f, m16, g, acc);
    #pragma unroll
    for (int nb = 0; nb < 8; ++nb)
        #pragma unroll
        for (int r = 0; r < 4; ++r) {
            int q   = q0 + wid*16 + g*4 + r;
            int gix = (nb*2 + (m16 >> 3)) ^ (q & 7);       // baked granule swizzle
            e2t[((size_t)b*HWN + q)*C2 + gix*8 + (m16 & 7)] = f2bf(acc[nb][r]);
        }

    proj_gemm(a, wgb, b_g, 1.f, m16, g, acc);
    #pragma unroll
    for (int nb = 0; nb < 8; ++nb)
        #pragma unroll
        for (int r = 0; r < 4; ++r)
            gs[nb*16 + m16][wid*16 + g*4 + r] = f2bf(acc[nb][r]);
    __syncthreads();
    // tiled + permuted + swizzled copy-out (this block == tile q0>>6)
    u16* gt = g2t + ((size_t)b*64 + (q0 >> 6))*8192;
    #pragma unroll
    for (int r = 0; r < 4; ++r) {
        int idx = r*256 + tid;            // 0..1023 -> row 0..127, c8 0..7
        int row = idx >> 3, c8 = idx & 7;
        union { u16 u[8]; int4 v; } o;
        #pragma unroll
        for (int e = 0; e < 8; ++e) {
            int c  = c8*8 + e;
            int cs = c ^ ((row & 7) << 3);                 // deswizzle dest col
            int kk = cs >> 5, rem = cs & 31;
            int gg = rem >> 3, jj = rem & 7;
            int ko = kk*32 + ((jj >> 2) << 4) + (gg << 2) + (jj & 3);  // k-perm
            o.u[e] = gs[row][ko];
        }
        *(int4*)&gt[row*64 + c8*8] = o.v;
    }
}

// ---------------- K2: flash core — r12 structure (KVBLK=128, k-split 2,
//   fixed m=0, swapped QK^T, in-register P, native exp2) + PHASE-STAGGERED
//   tile order: co-resident blocks start 8 tiles apart, so one block computes
//   while the other stages (legal: fixed-reference softmax is commutative). ----
__global__ __launch_bounds__(256, 2) void k_flash(
    const u16* __restrict__ e1t, const u16* __restrict__ e2t,
    const u16* __restrict__ g2t,
    u16* __restrict__ outp0, u16* __restrict__ outp1, float* __restrict__ ms)
{
    __shared__ u16 e2s[128*128];    // [k][c2] swizzled content, linear-staged (32KB)
    __shared__ u16 g2s[2*64*128];   // two [c2][64] permuted+swizzled subtiles (32KB)

    const int tid  = threadIdx.x;
    const int bid  = ((blockIdx.x & 7) << 6) | (blockIdx.x >> 3);  // XCD-chunked
    const int b    = bid >> 6;
    const int qb   = (bid >> 1) & 31;
    const int seg  = bid & 1;
    const int q0   = qb * 128;
    const int wid  = __builtin_amdgcn_readfirstlane(tid >> 6);
    const int lane = tid & 63;
    const int m16  = lane & 15;
    const int g    = lane >> 4;
    const int sw16 = (m16 & 7) << 3;
    // same-XCD dispatch neighbors (blockIdx 8 apart) get opposite phases
    const int phase = ((blockIdx.x >> 3) & 1) * 8;

    // e1 fragments (q side), in regs for whole kernel (log2e pre-scaled)
    s16x8 af[2][4];
    #pragma unroll
    for (int h = 0; h < 2; ++h) {
        const u16* p = e1t + ((size_t)b*HWN + q0 + wid*32 + h*16 + m16)*C2 + g*8;
        #pragma unroll
        for (int kc = 0; kc < 4; ++kc) af[h][kc] = *(const s16x8*)(p + kc*32);
    }

    f32x4 acc[2][8];
    #pragma unroll
    for (int h = 0; h < 2; ++h)
        #pragma unroll
        for (int i = 0; i < 8; ++i) acc[h][i] = (f32x4){0.f,0.f,0.f,0.f};
    float s_w = 0.f;

    const u16* e2base = e2t + (size_t)b*HWN*C2;
    const u16* g2base = g2t + (size_t)b*64*8192;

    for (int it = 0; it < 16; ++it) {
        const int itp = (it + phase) & 15;
        const int k0  = seg*2048 + itp*128;
        __syncthreads();                    // bar1: prev compute done, overwrite ok
        {                                   // stage: two contiguous 32 KB streams
            const u16* eG = e2base + (size_t)k0*C2;
            const u16* gG = g2base + (size_t)(k0 >> 6)*8192;
            #pragma unroll
            for (int r = 0; r < 8; ++r) {
                int off = (r*256 + tid)*8;
                int4 ve = *(const int4*)(eG + off);
                int4 vg = *(const int4*)(gG + off);
                *(int4*)&e2s[off] = ve;
                *(int4*)&g2s[off] = vg;
            }
        }
        __syncthreads();                    // bar2: tiles ready

        // ---- QK (swapped): S^T, lane m16 = q, regs cover k = j*16+g*4+r
        f32x4 s[2][8];
        #pragma unroll
        for (int h = 0; h < 2; ++h)
            #pragma unroll
            for (int j = 0; j < 8; ++j) s[h][j] = (f32x4){0.f,0.f,0.f,0.f};
        #pragma unroll
        for (int j = 0; j < 8; ++j) {
            #pragma unroll
            for (int kc = 0; kc < 4; ++kc) {
                s16x8 aa = *(const s16x8*)&e2s[((j*16+m16)*128 + kc*32 + g*8) ^ sw16];
                s[0][j] = __builtin_amdgcn_mfma_f32_16x16x32_bf16(aa, af[0][kc], s[0][j], 0, 0, 0);
                s[1][j] = __builtin_amdgcn_mfma_f32_16x16x32_bf16(aa, af[1][kc], s[1][j], 0, 0, 0);
            }
        }

        // ---- softmax with FIXED reference m=0: P = 2^S directly; s dies here
        float psum = 0.f;
        s16x8 pa[2][4];
        #pragma unroll
        for (int h = 0; h < 2; ++h)
            #pragma unroll
            for (int kk = 0; kk < 4; ++kk) {
                float p0 = fexp2(s[h][2*kk][0]);
                float p1 = fexp2(s[h][2*kk][1]);
                float p2 = fexp2(s[h][2*kk][2]);
                float p3 = fexp2(s[h][2*kk][3]);
                float p4 = fexp2(s[h][2*kk+1][0]);
                float p5 = fexp2(s[h][2*kk+1][1]);
                float p6 = fexp2(s[h][2*kk+1][2]);
                float p7 = fexp2(s[h][2*kk+1][3]);
                psum += ((p0 + p1) + (p2 + p3)) + ((p4 + p5) + (p6 + p7));
                union { u32 d[4]; s16x8 v; } pf;
                pf.d[0] = cvtpk(p0, p1);
                pf.d[1] = cvtpk(p2, p3);
                pf.d[2] = cvtpk(p4, p5);
                pf.d[3] = cvtpk(p6, p7);
                pa[h][kk] = pf.v;
            }
        s_w += psum;

        // ---- PV: acc[32q][128c2] += P[32q][128k'] * g2[128k'][128c2]
        #pragma unroll
        for (int kk = 0; kk < 4; ++kk) {
            const int sub = (kk >> 1) * 8192;
            #pragma unroll
            for (int fc = 0; fc < 8; ++fc) {
                s16x8 gb = *(const s16x8*)&g2s[sub + (fc*16+m16)*64 + (((kk&1)*32 + g*8) ^ sw16)];
                acc[0][fc] = __builtin_amdgcn_mfma_f32_16x16x32_bf16(pa[0][kk], gb, acc[0][fc], 0, 0, 0);
                acc[1][fc] = __builtin_amdgcn_mfma_f32_16x16x32_bf16(pa[1][kk], gb, acc[1][fc], 0, 0, 0);
            }
        }
    }

    // ---- epilogue
    #pragma unroll
    for (int off = 32; off >= 1; off >>= 1) s_w += __shfl_xor(s_w, off);
    if (lane == 0) {
        int idx = b*256 + seg*128 + qb*4 + wid;
        ms[idx*2 + 0] = 0.f;                 // fixed log2-reference
        ms[idx*2 + 1] = s_w;
    }
    const float inv_s = 1.f / s_w;
    u16* op = seg ? outp1 : outp0;
    #pragma unroll
    for (int h = 0; h < 2; ++h)
        #pragma unroll
        for (int fc = 0; fc < 8; ++fc)
            #pragma unroll
            for (int r = 0; r < 4; ++r)
                op[((size_t)b*HWN + q0 + wid*32 + h*16 + g*4 + r)*C2 + fc*16 + m16] =
                    f2bf(acc[h][fc][r] * inv_s);
}

// ---------------- K3: per-batch (M, Z) from 256 (m,s) pairs (log2 units) ------
__global__ void k_mz(const float* __restrict__ ms, float* __restrict__ mz)
{
    __shared__ float rmax[4], rsum[4];
    const int b = blockIdx.x, tid = threadIdx.x;
    const int lane = tid & 63, wid = tid >> 6;
    float m = ms[((size_t)b*256 + tid)*2 + 0];
    float s = ms[((size_t)b*256 + tid)*2 + 1];
    float mm = m;
    #pragma unroll
    for (int off = 32; off >= 1; off >>= 1) mm = fmaxf(mm, __shfl_xor(mm, off));
    if (lane == 0) rmax[wid] = mm;
    __syncthreads();
    float M = fmaxf(fmaxf(rmax[0], rmax[1]), fmaxf(rmax[2], rmax[3]));
    float z = s * fexp2(m - M);
    #pragma unroll
    for (int off = 32; off >= 1; off >>= 1) z += __shfl_xor(z, off);
    if (lane == 0) rsum[wid] = z;
    __syncthreads();
    if (tid == 0) { mz[b*2] = M; mz[b*2+1] = rsum[0]+rsum[1]+rsum[2]+rsum[3]; }
}

// ---------------- K4: combine k-split partials + final conv + residual --------
__global__ __launch_bounds__(256) void k_outM(
    const u16* __restrict__ outp0, const u16* __restrict__ outp1,
    const float* __restrict__ ms, const float* __restrict__ mz,
    const u16* __restrict__ woutb, const float* __restrict__ b_out,
    const float* __restrict__ x1, float* __restrict__ out)
{
    const int tid  = threadIdx.x;
    const int b    = blockIdx.x >> 6;
    const int q0   = (blockIdx.x & 63) * 64;
    const int wv   = tid >> 6;
    const int lane = tid & 63;
    const int m16  = lane & 15;
    const int g    = lane >> 4;
    const int q    = q0 + wv*16 + m16;

    const float M    = mz[b*2];
    const float invZ = 1.f / mz[b*2+1];
    const int idx5   = (q0 >> 5) + (wv >> 1);
    const float a0 = ms[(b*256 + idx5)*2+1]       * fexp2(ms[(b*256 + idx5)*2]       - M) * invZ;
    const float a1 = ms[(b*256 + 128 + idx5)*2+1] * fexp2(ms[(b*256 + 128 + idx5)*2] - M) * invZ;

    s16x8 bfr[4];
    #pragma unroll
    for (int ks = 0; ks < 4; ++ks) {
        union { s16x8 v; u16 u[8]; } o0, o1, oc;
        o0.v = *(const s16x8*)&outp0[((size_t)b*HWN + q)*C2 + ks*32 + g*8];
        o1.v = *(const s16x8*)&outp1[((size_t)b*HWN + q)*C2 + ks*32 + g*8];
        #pragma unroll
        for (int j = 0; j < 8; ++j)
            oc.u[j] = f2bf(a0*bf2f(o0.u[j]) + a1*bf2f(o1.u[j]));
        bfr[ks] = oc.v;
    }

    f32x4 acc[16];
    #pragma unroll
    for (int cb = 0; cb < 16; ++cb) acc[cb] = (f32x4){0.f,0.f,0.f,0.f};
    #pragma unroll
    for (int ks = 0; ks < 4; ++ks) {
        #pragma unroll
        for (int cb = 0; cb < 16; ++cb) {
            s16x8 afr = *(const s16x8*)&woutb[(size_t)(cb*16 + m16)*C2 + ks*32 + g*8];
            acc[cb] = __builtin_amdgcn_mfma_f32_16x16x32_bf16(afr, bfr[ks], acc[cb], 0, 0, 0);
        }
    }

    #pragma unroll
    for (int cb = 0; cb < 16; ++cb) {
        f32x4 bb = *(const f32x4*)&b_out[cb*16 + g*4];
        #pragma unroll
        for (int r = 0; r < 4; ++r) {
            int co = cb*16 + g*4 + r;
            size_t o = ((size_t)b*CC + co)*HWN + q;
            out[o] = acc[cb][r] + bb[r] + x1[o];
        }
    }
}

extern "C" void kernel_launch(void* const* d_in, const int* in_sizes, int n_in,
                              void* d_out, int out_size, void* d_ws, size_t ws_size,
                              hipStream_t stream)
{
    const float* x1   = (const float*)d_in[0];
    const float* x2   = (const float*)d_in[1];
    const float* w_th = (const float*)d_in[2];
    const float* b_th = (const float*)d_in[3];
    const float* w_pi = (const float*)d_in[4];
    const float* b_pi = (const float*)d_in[5];
    const float* w_g  = (const float*)d_in[6];
    const float* b_g  = (const float*)d_in[7];
    const float* w_out= (const float*)d_in[8];
    const float* b_out= (const float*)d_in[9];
    float* out = (float*)d_out;

    char* ws = (char*)d_ws;
    u16*   e1t  = (u16*)(ws);                    // 8 MiB  bf16 [B][HW][C2]
    u16*   e2t  = (u16*)(ws + 8388608);          // 8 MiB  bf16 [B][HW][C2] (swizzled)
    u16*   g2t  = (u16*)(ws + 16777216);         // 8 MiB  bf16 [B][64][128][64] tiled
    u16*   outp0= (u16*)(ws + 25165824);         // 8 MiB  bf16 seg0 partial
    u16*   outp1= (u16*)(ws + 33554432);         // 8 MiB  bf16 seg1 partial
    float* ms   = (float*)(ws + 41943040);       // 16 KiB f32  [B][256][2]
    float* mz   = (float*)(ws + 41959424);       // 64 B   f32  [B][2]
    u16*   wthb = (u16*)(ws + 41959488);         // 64 KiB bf16 [C2][CC] (log2e-scaled)
    u16*   wpib = (u16*)(ws + 42025024);         // 64 KiB
    u16*   wgb  = (u16*)(ws + 42090560);         // 64 KiB
    u16*   woutb= (u16*)(ws + 42156096);         // 64 KiB bf16 [CC][C2]

    k_wcvt <<<dim3(128), dim3(256), 0, stream>>>(w_th, w_pi, w_g, w_out, wthb, wpib, wgb, woutb);
    k_projM<<<dim3(512), dim3(256), 0, stream>>>(x1, x2, wthb, b_th, wpib, b_pi, wgb, b_g,
                                                 e1t, e2t, g2t);
    k_flash<<<dim3(512), dim3(256), 0, stream>>>(e1t, e2t, g2t, outp0, outp1, ms);
    k_mz   <<<dim3(8),   dim3(256), 0, stream>>>(ms, mz);
    k_outM <<<dim3(512), dim3(256), 0, stream>>>(outp0, outp1, ms, mz, woutb, b_out, x1, out);
}